// Round 5
// baseline (483.655 us; speedup 1.0000x reference)
//
#include <hip/hip_runtime.h>
#include <hip/hip_bf16.h>

// KroneckerMixer: B=64, N=1024, K=64, BASIS=8, T=0.2, 20 sinkhorn iters.
// R5 pipeline (bf16 path, ws >= 37 MB):
//   k_front : fused. Blocks 0..63  = A-sinkhorn (multiplicative Sinkhorn-Knopp,
//             fence-free grid barrier: all cross-block traffic via agent-scope
//             RELAXED atomics = sc1 cache-bypass; 1 barrier/iter, ping-pong P,
//             redundant full-v reduce into LDS). Emits Ah/Al bf16 hi/lo.
//             Blocks 64..319 = W-path: per-n 64x64 sinkhorn (1024 thr, 4 n's
//             sequential) + x_local matmul -> XL fp32 [n][c].
//   k_xt    : transpose + hi/lo split XL -> XTh/XTl bf16 [c][n].
//   k_gemm3 : out = Ah*XTh + Al*XTh + Ah*XTl via mfma_f32_16x16x32_bf16.
// Fallback (small ws): k_front writes fp32 A; fp32 k_gemm.
//
// R5 fix: R4 zeroed only 1024 B of ctrl but gbar2's leaf counters extend to
// byte 1156 -> leaf groups 6-7 started at 0xAA poison -> barrier never
// completed -> hang. Now memset 4096 B.

#define N_DIM 1024
#define INV_T 5.0f

typedef __attribute__((ext_vector_type(8))) short short8;
typedef __attribute__((ext_vector_type(4))) float float4v;

// ---------------- wave64 sum reduction via DPP (VALU pipe) -------------------
// Result valid in lane 63.
__device__ __forceinline__ float wave_red_sum(float x) {
#define DPP_ADD(C)                                                            \
  {                                                                           \
    int _y = __builtin_amdgcn_update_dpp(0, __float_as_int(x), (C), 0xf, 0xf, \
                                         true);                               \
    x += __int_as_float(_y);                                                  \
  }
  DPP_ADD(0x111);
  DPP_ADD(0x112);
  DPP_ADD(0x114);
  DPP_ADD(0x118);
  DPP_ADD(0x142);
  DPP_ADD(0x143);
#undef DPP_ADD
  return x;
}

// ---- fence-free grid barrier over blocks 0..63, 8-leaf tree, monotonic ------
// ctrl layout (unsigned): gen@0, root@32, leaf[g]@64+32g  (byte 1156 max,
// ctrl region is 4096 B, all zeroed by launcher).
// No acq/rel: counters are sc1-bypass atomics; payload (P) is also sc1-bypass,
// ordered by __syncthreads' vmcnt(0) drain before arrival + same-address RMW
// serialization + control deps up the tree. bi = barrier index (0..19).
__device__ __forceinline__ void gbar2(unsigned* ctrl, int bid, int bi) {
  __syncthreads();  // drains ALL threads' vmem (incl. bypass stores) first
  if (threadIdx.x == 0) {
    unsigned* gen = ctrl;
    unsigned* root = ctrl + 32;
    unsigned* leaf = ctrl + 64 + (bid >> 3) * 32;
    const unsigned tgt = (unsigned)bi * 8u + 7u;
    unsigned a = __hip_atomic_fetch_add(leaf, 1u, __ATOMIC_RELAXED,
                                        __HIP_MEMORY_SCOPE_AGENT);
    if (a == tgt) {  // last of this 8-block leaf group
      unsigned r = __hip_atomic_fetch_add(root, 1u, __ATOMIC_RELAXED,
                                          __HIP_MEMORY_SCOPE_AGENT);
      if (r == tgt) {  // last leaf group overall
        __hip_atomic_fetch_add(gen, 1u, __ATOMIC_RELAXED,
                               __HIP_MEMORY_SCOPE_AGENT);
      } else {
        while (__hip_atomic_load(gen, __ATOMIC_RELAXED,
                                 __HIP_MEMORY_SCOPE_AGENT) <= (unsigned)bi)
          __builtin_amdgcn_s_sleep(1);
      }
    } else {
      while (__hip_atomic_load(gen, __ATOMIC_RELAXED,
                               __HIP_MEMORY_SCOPE_AGENT) <= (unsigned)bi)
        __builtin_amdgcn_s_sleep(1);
    }
  }
  __syncthreads();
}

// ---------------- kernel 1: fused sinkA + wpath ------------------------------
// grid 320 x 1024. LDS union: sinkA {v_s[1024], uS[16]},
// wpath {uS2[64], ps[16*64], Ws[4096], Xs[64*65]} = 9344 floats.
__global__ __launch_bounds__(1024) void k_front(
    const float* __restrict__ x, const float* __restrict__ L,
    const float* __restrict__ W1, const float* __restrict__ WV,
    float* __restrict__ A, __hip_bfloat16* __restrict__ Ah,
    __hip_bfloat16* __restrict__ Al, float* __restrict__ P,
    unsigned* __restrict__ ctrl, float* __restrict__ XL, int write_bf16) {
  __shared__ __align__(16) float smem[9600];
  const int t = threadIdx.x;
  const int bid = blockIdx.x;
  const int lane = t & 63;
  const int w = t >> 6;  // 0..15

  if (bid < 64) {
    // =================== A-sinkhorn role ===================
    float* v_s = smem;        // [1024]
    float* uS = smem + 1024;  // [16]
    const int b = bid;
    const int r0 = b * 16;

    float e_c[16];
#pragma unroll
    for (int i = 0; i < 16; ++i)
      e_c[i] = __expf(L[(r0 + i) * N_DIM + t] * INV_T);

    float e_r[16];
    {
      const float4* src =
          (const float4*)(L + (size_t)(r0 + w) * N_DIM + lane * 16);
#pragma unroll
      for (int q = 0; q < 4; ++q) {
        float4 f = src[q];
        e_r[4 * q + 0] = __expf(f.x * INV_T);
        e_r[4 * q + 1] = __expf(f.y * INV_T);
        e_r[4 * q + 2] = __expf(f.z * INV_T);
        e_r[4 * q + 3] = __expf(f.w * INV_T);
      }
    }

    for (int it = 0; it < 20; ++it) {
      // ---- row pass: u_m = 1 / sum_n E0[m][n] * v[n]  (v from LDS)
      float p = 0.f;
      if (it == 0) {
#pragma unroll
        for (int j = 0; j < 16; ++j) p += e_r[j];
      } else {
#pragma unroll
        for (int q = 0; q < 4; ++q) {
          float4 f = *(const float4*)&v_s[lane * 16 + 4 * q];
          p += e_r[4 * q + 0] * f.x + e_r[4 * q + 1] * f.y +
               e_r[4 * q + 2] * f.z + e_r[4 * q + 3] * f.w;
        }
      }
      p = wave_red_sum(p);
      if (lane == 63) uS[w] = 1.0f / p;
      __syncthreads();
      // ---- col partials -> P[par][b][t]  (sc1 bypass store, no L2 dirt)
      float cp = 0.f;
#pragma unroll
      for (int i = 0; i < 16; ++i) cp += e_c[i] * uS[i];
      float* Pw = P + (it & 1) * 65536;
      __hip_atomic_store(&Pw[b * N_DIM + t], cp, __ATOMIC_RELAXED,
                         __HIP_MEMORY_SCOPE_AGENT);
      gbar2(ctrl, bid, it);
      // ---- redundant full-v reduce: thread t owns col t
      float s2 = 0.f;
#pragma unroll
      for (int pb = 0; pb < 64; ++pb)
        s2 += __hip_atomic_load(&Pw[pb * N_DIM + t], __ATOMIC_RELAXED,
                                __HIP_MEMORY_SCOPE_AGENT);
      v_s[t] = 1.0f / s2;
      __syncthreads();
    }
    // ---- final A = E0 * u (x) v
    const float vt = v_s[t];
#pragma unroll
    for (int i = 0; i < 16; ++i) {
      float a = e_c[i] * uS[i] * vt;
      if (write_bf16) {
        __hip_bfloat16 h = __float2bfloat16(a);
        Ah[(size_t)(r0 + i) * N_DIM + t] = h;
        Al[(size_t)(r0 + i) * N_DIM + t] =
            __float2bfloat16(a - __bfloat162float(h));
      } else {
        A[(size_t)(r0 + i) * N_DIM + t] = a;
      }
    }
  } else {
    // =================== W-path role: 4 n's sequentially ===================
    float* uS2 = smem;                    // [64]
    float* ps = smem + 64;                // [16][64]
    float* Ws = smem + 64 + 1024;         // [64*64]
    float* Xs = smem + 64 + 1024 + 4096;  // [64*65]
    const int base_n = (bid - 64) * 4;

    for (int s = 0; s < 4; ++s) {
      const int n = base_n + s;
      float w1[8];
#pragma unroll
      for (int k = 0; k < 8; ++k) w1[k] = W1[n * 8 + k];

      // element j: (row i = j*16 + w, col o = lane)
      float ew[4];
#pragma unroll
      for (int j = 0; j < 4; ++j) {
        const int f = j * 1024 + t;
        float acc = 0.f;
#pragma unroll
        for (int k = 0; k < 8; ++k) acc += w1[k] * WV[k * 4096 + f];
        ew[j] = __expf(acc * INV_T);
      }

      float vt = 1.0f;
      for (int it = 0; it < 20; ++it) {
        // row pass: wave w owns rows {j*16+w}; full row within one wave
#pragma unroll
        for (int j = 0; j < 4; ++j) {
          float pp = wave_red_sum(ew[j] * vt);
          if (lane == 63) uS2[j * 16 + w] = 1.0f / pp;
        }
        // uS2[j*16+w] written & read by the same wave: in-order LDS pipe
        float cp = 0.f;
#pragma unroll
        for (int j = 0; j < 4; ++j) cp += ew[j] * uS2[j * 16 + w];
        ps[w * 64 + lane] = cp;
        __syncthreads();
        float sv = 0.f;
#pragma unroll
        for (int ww = 0; ww < 16; ++ww) sv += ps[ww * 64 + lane];
        vt = 1.0f / sv;
        __syncthreads();
      }

      // W into LDS; stage x tile
#pragma unroll
      for (int j = 0; j < 4; ++j)
        Ws[(j * 16 + w) * 64 + lane] = ew[j] * uS2[j * 16 + w] * vt;
#pragma unroll
      for (int j = 0; j < 4; ++j) {
        const int idx = j * 1024 + t;  // batch bb = idx>>6, col i = idx&63
        Xs[(idx >> 6) * 65 + (idx & 63)] =
            x[(size_t)(idx >> 6) * 65536 + n * 64 + (idx & 63)];
      }
      __syncthreads();

      // x_local[bb][o] = sum_i Xs[bb][i] * Ws[i][o]; thread = (bb, 4 o's)
      const int bb = t >> 4;
      const int o4 = (t & 15) * 4;
      float4 a4 = {0.f, 0.f, 0.f, 0.f};
#pragma unroll 4
      for (int i = 0; i < 64; ++i) {
        float4 w4 = *(const float4*)&Ws[i * 64 + o4];
        float xv = Xs[bb * 65 + i];
        a4.x += xv * w4.x;
        a4.y += xv * w4.y;
        a4.z += xv * w4.z;
        a4.w += xv * w4.w;
      }
      *(float4*)&XL[(size_t)n * 4096 + bb * 64 + o4] = a4;
      __syncthreads();  // before next n reuses LDS
    }
  }
}

// ---------------- kernel 2b: transpose + hi/lo split -------------------------
// XL fp32 [n=1024][c=4096] -> XTh/XTl bf16 [c=4096][n=1024].
__global__ __launch_bounds__(256) void k_xt(const float* __restrict__ XL,
                                            __hip_bfloat16* __restrict__ XTh,
                                            __hip_bfloat16* __restrict__ XTl) {
  __shared__ float T[64 * 68];
  const int t = threadIdx.x;
  const int n0 = blockIdx.x * 64;
  const int c0 = blockIdx.y * 64;
  {
    const int r = t >> 4;         // 0..15
    const int c4 = (t & 15) * 4;  // 0..60
#pragma unroll
    for (int p = 0; p < 4; ++p) {
      float4 f =
          *(const float4*)&XL[(size_t)(n0 + r + 16 * p) * 4096 + c0 + c4];
      *(float4*)&T[(r + 16 * p) * 68 + c4] = f;
    }
  }
  __syncthreads();
  const int cl = t >> 2;        // 0..63
  const int nb = (t & 3) * 16;  // 0,16,32,48
  __align__(16) __hip_bfloat16 hbuf[16];
  __align__(16) __hip_bfloat16 lbuf[16];
#pragma unroll
  for (int j = 0; j < 16; ++j) {
    float xv = T[(nb + j) * 68 + cl];
    __hip_bfloat16 h = __float2bfloat16(xv);
    hbuf[j] = h;
    lbuf[j] = __float2bfloat16(xv - __bfloat162float(h));
  }
  const size_t off = (size_t)(c0 + cl) * 1024 + n0 + nb;
  *(uint4*)&XTh[off] = *(uint4*)&hbuf[0];
  *(uint4*)&XTh[off + 8] = *(uint4*)&hbuf[8];
  *(uint4*)&XTl[off] = *(uint4*)&lbuf[0];
  *(uint4*)&XTl[off + 8] = *(uint4*)&lbuf[8];
}

// ---------------- kernel 3 (bf16): out = Ah*XTh + Al*XTh + Ah*XTl ------------
// D[m=1024][c=4096], 128x128 block tile, 4 waves each 64x64 of 16x16x32 MFMA.
#define LSTR 72  // padded LDS row stride (elements)
__global__ __launch_bounds__(256) void k_gemm3(
    const ushort* __restrict__ Ah, const ushort* __restrict__ Al,
    const ushort* __restrict__ XTh, const ushort* __restrict__ XTl,
    float* __restrict__ out) {
  __shared__ ushort As[128 * LSTR];
  __shared__ ushort Xs[128 * LSTR];
  const int t = threadIdx.x;
  const int m0 = blockIdx.x * 128;
  const int c0 = blockIdx.y * 128;
  const int wid = t >> 6, lane = t & 63;
  const int wm = (wid & 1) * 64, wc = (wid >> 1) * 64;
  const int lm = lane & 15, q = lane >> 4;
  const int sr = t >> 1;        // staging row 0..127
  const int sc = (t & 1) * 32;  // staging k-offset: [sc, sc+32)

  float4v acc[4][4];
#pragma unroll
  for (int i = 0; i < 4; ++i)
#pragma unroll
    for (int j = 0; j < 4; ++j) acc[i][j] = (float4v){0.f, 0.f, 0.f, 0.f};

  for (int seg = 0; seg < 3; ++seg) {
    const ushort* Ag = (seg == 1) ? Al : Ah;
    const ushort* Xg = (seg == 2) ? XTl : XTh;
    for (int k0 = 0; k0 < 1024; k0 += 64) {
      __syncthreads();
      const ushort* ag = Ag + (size_t)(m0 + sr) * 1024 + k0 + sc;
      const ushort* xg = Xg + (size_t)(c0 + sr) * 1024 + k0 + sc;
      uint4 a0 = *(const uint4*)(ag);
      uint4 a1 = *(const uint4*)(ag + 8);
      uint4 a2 = *(const uint4*)(ag + 16);
      uint4 a3 = *(const uint4*)(ag + 24);
      uint4 x0 = *(const uint4*)(xg);
      uint4 x1 = *(const uint4*)(xg + 8);
      uint4 x2 = *(const uint4*)(xg + 16);
      uint4 x3 = *(const uint4*)(xg + 24);
      *(uint4*)&As[sr * LSTR + sc] = a0;
      *(uint4*)&As[sr * LSTR + sc + 8] = a1;
      *(uint4*)&As[sr * LSTR + sc + 16] = a2;
      *(uint4*)&As[sr * LSTR + sc + 24] = a3;
      *(uint4*)&Xs[sr * LSTR + sc] = x0;
      *(uint4*)&Xs[sr * LSTR + sc + 8] = x1;
      *(uint4*)&Xs[sr * LSTR + sc + 16] = x2;
      *(uint4*)&Xs[sr * LSTR + sc + 24] = x3;
      __syncthreads();
#pragma unroll
      for (int kk = 0; kk < 2; ++kk) {
        short8 af[4], xf[4];
#pragma unroll
        for (int i = 0; i < 4; ++i)
          af[i] = *(const short8*)&As[(wm + 16 * i + lm) * LSTR + kk * 32 +
                                      q * 8];
#pragma unroll
        for (int j = 0; j < 4; ++j)
          xf[j] = *(const short8*)&Xs[(wc + 16 * j + lm) * LSTR + kk * 32 +
                                      q * 8];
#pragma unroll
        for (int i = 0; i < 4; ++i)
#pragma unroll
          for (int j = 0; j < 4; ++j)
            acc[i][j] = __builtin_amdgcn_mfma_f32_16x16x32_bf16(
                af[i], xf[j], acc[i][j], 0, 0, 0);
      }
    }
  }
  // epilogue: D row = q*4 + reg, col = lm  (m89-verified C/D layout)
#pragma unroll
  for (int i = 0; i < 4; ++i) {
#pragma unroll
    for (int j = 0; j < 4; ++j) {
      const int m = m0 + wm + 16 * i + q * 4;
      const int c = c0 + wc + 16 * j + lm;
      const int bb = c >> 6, o = c & 63;
      float* dst = out + (size_t)bb * 65536 + (size_t)m * 64 + o;
#pragma unroll
      for (int r = 0; r < 4; ++r) dst[64 * r] = acc[i][j][r];
    }
  }
}

// ---------------- kernel 3 (fp32 fallback) -----------------------------------
__global__ __launch_bounds__(256) void k_gemm(const float* __restrict__ A,
                                              const float* __restrict__ XL,
                                              float* __restrict__ out) {
  __shared__ float Asm[32][132];
  __shared__ float Xsm[32][132];
  const int t = threadIdx.x;
  const int m0 = blockIdx.x * 128;
  const int c0 = blockIdx.y * 128;
  const int my8 = (t >> 4) * 8;
  const int cx8 = (t & 15) * 8;
  const int kk = t & 31;
  const int rr = t >> 5;
  float acc[8][8] = {};

  for (int k0 = 0; k0 < 1024; k0 += 32) {
#pragma unroll
    for (int s = 0; s < 16; ++s)
      Asm[kk][rr + 8 * s] = A[(size_t)(m0 + rr + 8 * s) * 1024 + k0 + kk];
#pragma unroll
    for (int s = 0; s < 4; ++s) {
      float4 f = *(const float4*)&XL[(size_t)(k0 + rr + 8 * s) * 4096 + c0 +
                                     kk * 4];
      *(float4*)&Xsm[rr + 8 * s][kk * 4] = f;
    }
    __syncthreads();
#pragma unroll
    for (int k = 0; k < 32; ++k) {
      float a[8], xv[8];
      *(float4*)&a[0] = *(const float4*)&Asm[k][my8];
      *(float4*)&a[4] = *(const float4*)&Asm[k][my8 + 4];
      *(float4*)&xv[0] = *(const float4*)&Xsm[k][cx8];
      *(float4*)&xv[4] = *(const float4*)&Xsm[k][cx8 + 4];
#pragma unroll
      for (int i = 0; i < 8; ++i)
#pragma unroll
        for (int j = 0; j < 8; ++j) acc[i][j] += a[i] * xv[j];
    }
    __syncthreads();
  }

#pragma unroll
  for (int i = 0; i < 8; ++i) {
    const int m = m0 + my8 + i;
    const int c = c0 + cx8;
    const int bb = c >> 6, o = c & 63;
    float* dst = out + (size_t)bb * 65536 + (size_t)m * 64 + o;
    *(float4*)&dst[0] = *(float4*)&acc[i][0];
    *(float4*)&dst[4] = *(float4*)&acc[i][4];
  }
}

// ---------------- launcher ---------------------------------------------------
extern "C" void kernel_launch(void* const* d_in, const int* in_sizes, int n_in,
                              void* d_out, int out_size, void* d_ws,
                              size_t ws_size, hipStream_t stream) {
  (void)in_sizes;
  (void)n_in;
  (void)out_size;
  const float* x = (const float*)d_in[0];
  const float* Alog = (const float*)d_in[1];
  const float* W1 = (const float*)d_in[2];
  const float* WV = (const float*)d_in[3];
  float* out = (float*)d_out;

  char* ws = (char*)d_ws;
  const size_t MB = 1024 * 1024;
  const bool use_bf16 = ws_size >= 37 * MB;

  float* A;
  float* P;
  unsigned* ctrl;
  float* XL;
  __hip_bfloat16 *Ah = nullptr, *Al = nullptr, *XTh = nullptr, *XTl = nullptr;
  if (use_bf16) {
    P = (float*)(ws);                       // 512 KB (2x ping-pong)
    ctrl = (unsigned*)(ws + 512 * 1024);    // 4 KB zeroed
    XL = (float*)(ws + 1 * MB);             // 16 MB -> ends 17 MB
    Ah = (__hip_bfloat16*)(ws + 17 * MB);   // 2 MB
    Al = (__hip_bfloat16*)(ws + 19 * MB);   // 2 MB
    XTh = (__hip_bfloat16*)(ws + 21 * MB);  // 8 MB
    XTl = (__hip_bfloat16*)(ws + 29 * MB);  // 8 MB -> ends 37 MB
    A = (float*)ws;                         // unused in bf16 mode
  } else {
    A = (float*)(ws);                       // 4 MB
    P = (float*)(ws + 4 * MB);              // 512 KB
    ctrl = (unsigned*)(ws + 4 * MB + 512 * 1024);
    XL = (float*)(ws + 5 * MB);             // 16 MB -> ends 21 MB
  }

  hipMemsetAsync(ctrl, 0, 4096, stream);  // MUST cover all tree counters
  hipLaunchKernelGGL(k_front, dim3(320), dim3(1024), 0, stream, x, Alog, W1,
                     WV, A, Ah, Al, P, ctrl, XL, use_bf16 ? 1 : 0);
  if (use_bf16) {
    hipLaunchKernelGGL(k_xt, dim3(16, 64), dim3(256), 0, stream, XL, XTh, XTl);
    hipLaunchKernelGGL(k_gemm3, dim3(8, 32), dim3(256), 0, stream,
                       (const ushort*)Ah, (const ushort*)Al,
                       (const ushort*)XTh, (const ushort*)XTl, out);
  } else {
    hipLaunchKernelGGL(k_gemm, dim3(8, 32), dim3(256), 0, stream, A, XL, out);
  }
}

// Round 6
// 353.899 us; speedup vs baseline: 1.3666x; 1.3666x over previous
//
#include <hip/hip_runtime.h>
#include <hip/hip_bf16.h>

// KroneckerMixer: B=64, N=1024, K=64, BASIS=8, T=0.2, 20 sinkhorn iters.
// R6 pipeline (bf16 path, ws >= 40.25 MB):
//   k_front : fused.
//     Blocks 0..15  = A-sinkhorn u/v solver: 64 rows/block, E0 fp32 staged in
//       ws (iter0 computes exp(L/T), writes E0 + Eh/El bf16 hi/lo), then
//       row/col passes STREAM E0 from the XCD-local L2. Cross-block exchange:
//       1 sc1 store + 16 sc1 loads per thread per iter (ping-pong P), one flat
//       16-way relaxed barrier per iter. Emits u,v (A = u (x) E0 (x) v folded
//       into the GEMM).
//     Blocks 16..271 = W-path (R5-verified): per-n 64x64 sinkhorn + x_local
//       matmul -> XL fp32 [n][c].
//   k_xt    : transpose + v-scale + hi/lo split XL -> XTh/XTl bf16 [c][n].
//   k_gemm3 : out[m][c] = u_m*(Eh*XTh + El*XTh + Eh*XTl) via mfma 16x16x32 bf16.
// Fallback (small ws): fp32 k_gemm reading E0 with u/v folded.

#define N_DIM 1024
#define INV_T 5.0f
#define NBAR 16  // A-sinkhorn barrier blocks

typedef __attribute__((ext_vector_type(8))) short short8;
typedef __attribute__((ext_vector_type(4))) float float4v;

// ---------------- wave64 sum reduction via DPP (VALU pipe) -------------------
// Result valid in lane 63.
__device__ __forceinline__ float wave_red_sum(float x) {
#define DPP_ADD(C)                                                            \
  {                                                                           \
    int _y = __builtin_amdgcn_update_dpp(0, __float_as_int(x), (C), 0xf, 0xf, \
                                         true);                               \
    x += __int_as_float(_y);                                                  \
  }
  DPP_ADD(0x111);
  DPP_ADD(0x112);
  DPP_ADD(0x114);
  DPP_ADD(0x118);
  DPP_ADD(0x142);
  DPP_ADD(0x143);
#undef DPP_ADD
  return x;
}

// ---- flat 16-way grid barrier, monotonic, fully relaxed (sc1 counters) ------
// All cross-block payload moves via sc1 (agent-scope relaxed) accesses, so no
// acquire/release cache maintenance is needed anywhere. Producer stores are
// globally visible before arrival via the compiler's vmcnt(0) drain at
// __syncthreads. ctrl: gen@word0, cnt@word32 (separate lines, zeroed 4096 B).
__device__ __forceinline__ void gbar3(unsigned* ctrl, int bi) {
  __syncthreads();
  if (threadIdx.x == 0) {
    unsigned* gen = ctrl;
    unsigned* cnt = ctrl + 32;
    unsigned a = __hip_atomic_fetch_add(cnt, 1u, __ATOMIC_RELAXED,
                                        __HIP_MEMORY_SCOPE_AGENT);
    if (a == (unsigned)bi * (unsigned)NBAR + (unsigned)(NBAR - 1)) {
      __hip_atomic_fetch_add(gen, 1u, __ATOMIC_RELAXED,
                             __HIP_MEMORY_SCOPE_AGENT);
    } else {
      while (__hip_atomic_load(gen, __ATOMIC_RELAXED,
                               __HIP_MEMORY_SCOPE_AGENT) <= (unsigned)bi)
        __builtin_amdgcn_s_sleep(2);
    }
  }
  __syncthreads();
}

// ---------------- kernel 1: fused sinkA(u,v) + wpath -------------------------
// grid 272 x 1024.
__global__ __launch_bounds__(1024) void k_front(
    const float* __restrict__ x, const float* __restrict__ L,
    const float* __restrict__ W1, const float* __restrict__ WV,
    float* __restrict__ E0, __hip_bfloat16* __restrict__ Eh,
    __hip_bfloat16* __restrict__ El, float* __restrict__ P,
    unsigned* __restrict__ ctrl, float* __restrict__ u_g,
    float* __restrict__ v_g, float* __restrict__ XL, int write_bf16) {
  __shared__ __align__(16) float smem[9600];
  const int t = threadIdx.x;
  const int bid = blockIdx.x;
  const int lane = t & 63;
  const int w = t >> 6;  // 0..15

  if (bid < NBAR) {
    // =================== A-sinkhorn u/v role ===================
    float* v_s = smem;        // [1024]
    float* uS = smem + 1024;  // [64]  (local-row u)
    const int b = bid;
    const int r0 = b * 64;

    for (int it = 0; it < 20; ++it) {
      // ---- row pass: u_i = 1/sum_c E0[i][c]*v[c]; wave w owns rows 4w..4w+3
      float p[4] = {0.f, 0.f, 0.f, 0.f};
      if (it == 0) {
#pragma unroll
        for (int j = 0; j < 4; ++j) {
          const int r = r0 + 4 * w + j;
          const float4* Lr = (const float4*)(L + (size_t)r * N_DIM + lane * 16);
          float4* Er = (float4*)(E0 + (size_t)r * N_DIM + lane * 16);
          float e[16];
#pragma unroll
          for (int q = 0; q < 4; ++q) {
            float4 f = Lr[q];
            float4 g;
            g.x = __expf(f.x * INV_T);
            g.y = __expf(f.y * INV_T);
            g.z = __expf(f.z * INV_T);
            g.w = __expf(f.w * INV_T);
            Er[q] = g;
            e[4 * q + 0] = g.x;
            e[4 * q + 1] = g.y;
            e[4 * q + 2] = g.z;
            e[4 * q + 3] = g.w;
            p[j] += g.x + g.y + g.z + g.w;
          }
          if (write_bf16) {
            __align__(16) ushort hb[16], lb[16];
#pragma unroll
            for (int q = 0; q < 16; ++q) {
              __hip_bfloat16 h = __float2bfloat16(e[q]);
              hb[q] = *(ushort*)&h;
              __hip_bfloat16 l = __float2bfloat16(e[q] - __bfloat162float(h));
              lb[q] = *(ushort*)&l;
            }
            const size_t off = (size_t)r * N_DIM + lane * 16;
            *(uint4*)&Eh[off] = *(uint4*)&hb[0];
            *(uint4*)&Eh[off + 8] = *(uint4*)&hb[8];
            *(uint4*)&El[off] = *(uint4*)&lb[0];
            *(uint4*)&El[off + 8] = *(uint4*)&lb[8];
          }
        }
      } else {
#pragma unroll
        for (int j = 0; j < 4; ++j) {
          const int r = r0 + 4 * w + j;
          const float4* Er = (const float4*)(E0 + (size_t)r * N_DIM + lane * 16);
#pragma unroll
          for (int q = 0; q < 4; ++q) {
            float4 e = Er[q];
            float4 vv = *(const float4*)&v_s[lane * 16 + 4 * q];
            p[j] += e.x * vv.x + e.y * vv.y + e.z * vv.z + e.w * vv.w;
          }
        }
      }
#pragma unroll
      for (int j = 0; j < 4; ++j) {
        float pr = wave_red_sum(p[j]);
        if (lane == 63) uS[4 * w + j] = 1.0f / pr;
      }
      __syncthreads();
      // ---- col pass: this block's partial col sums (thread t owns col t)
      float cp = 0.f;
#pragma unroll 8
      for (int r = 0; r < 64; ++r)
        cp += E0[(size_t)(r0 + r) * N_DIM + t] * uS[r];
      float* Pw = P + (it & 1) * (NBAR * N_DIM);
      __hip_atomic_store(&Pw[b * N_DIM + t], cp, __ATOMIC_RELAXED,
                         __HIP_MEMORY_SCOPE_AGENT);
      gbar3(ctrl, it);
      // ---- v update: 16 sc1 loads per thread (one per partial block)
      float s2 = 0.f;
#pragma unroll
      for (int pb = 0; pb < NBAR; ++pb)
        s2 += __hip_atomic_load(&Pw[pb * N_DIM + t], __ATOMIC_RELAXED,
                                __HIP_MEMORY_SCOPE_AGENT);
      v_s[t] = 1.0f / s2;
      __syncthreads();
    }
    // ---- epilogue: emit u (this block's 64 rows) and v (block 0)
    if (t < 64) u_g[r0 + t] = uS[t];
    if (b == 0) v_g[t] = v_s[t];
  } else {
    // =================== W-path role: 4 n's sequentially ===================
    float* uS2 = smem;                    // [64]
    float* ps = smem + 64;                // [16][64]
    float* Ws = smem + 64 + 1024;         // [64*64]
    float* Xs = smem + 64 + 1024 + 4096;  // [64*65]
    const int base_n = (bid - NBAR) * 4;

    for (int s = 0; s < 4; ++s) {
      const int n = base_n + s;
      float w1[8];
#pragma unroll
      for (int k = 0; k < 8; ++k) w1[k] = W1[n * 8 + k];

      // element j: (row i = j*16 + w, col o = lane)
      float ew[4];
#pragma unroll
      for (int j = 0; j < 4; ++j) {
        const int f = j * 1024 + t;
        float acc = 0.f;
#pragma unroll
        for (int k = 0; k < 8; ++k) acc += w1[k] * WV[k * 4096 + f];
        ew[j] = __expf(acc * INV_T);
      }

      float vt = 1.0f;
      for (int it = 0; it < 20; ++it) {
#pragma unroll
        for (int j = 0; j < 4; ++j) {
          float pp = wave_red_sum(ew[j] * vt);
          if (lane == 63) uS2[j * 16 + w] = 1.0f / pp;
        }
        // uS2[j*16+w] written & read by the same wave: in-order LDS pipe
        float cp = 0.f;
#pragma unroll
        for (int j = 0; j < 4; ++j) cp += ew[j] * uS2[j * 16 + w];
        ps[w * 64 + lane] = cp;
        __syncthreads();
        float sv = 0.f;
#pragma unroll
        for (int ww = 0; ww < 16; ++ww) sv += ps[ww * 64 + lane];
        vt = 1.0f / sv;
        __syncthreads();
      }

#pragma unroll
      for (int j = 0; j < 4; ++j)
        Ws[(j * 16 + w) * 64 + lane] = ew[j] * uS2[j * 16 + w] * vt;
#pragma unroll
      for (int j = 0; j < 4; ++j) {
        const int idx = j * 1024 + t;  // batch bb = idx>>6, col i = idx&63
        Xs[(idx >> 6) * 65 + (idx & 63)] =
            x[(size_t)(idx >> 6) * 65536 + n * 64 + (idx & 63)];
      }
      __syncthreads();

      // x_local[bb][o] = sum_i Xs[bb][i] * Ws[i][o]; thread = (bb, 4 o's)
      const int bb = t >> 4;
      const int o4 = (t & 15) * 4;
      float4 a4 = {0.f, 0.f, 0.f, 0.f};
#pragma unroll 4
      for (int i = 0; i < 64; ++i) {
        float4 w4 = *(const float4*)&Ws[i * 64 + o4];
        float xv = Xs[bb * 65 + i];
        a4.x += xv * w4.x;
        a4.y += xv * w4.y;
        a4.z += xv * w4.z;
        a4.w += xv * w4.w;
      }
      *(float4*)&XL[(size_t)n * 4096 + bb * 64 + o4] = a4;
      __syncthreads();  // before next n reuses LDS
    }
  }
}

// ---------------- kernel 2b: transpose + v-scale + hi/lo split ---------------
// XTh/XTl[c][n] = hi/lo bf16 of (v[n] * XL[n][c]).
__global__ __launch_bounds__(256) void k_xt(const float* __restrict__ XL,
                                            const float* __restrict__ v_g,
                                            __hip_bfloat16* __restrict__ XTh,
                                            __hip_bfloat16* __restrict__ XTl) {
  __shared__ float T[64 * 68];
  __shared__ float vsh[64];
  const int t = threadIdx.x;
  const int n0 = blockIdx.x * 64;
  const int c0 = blockIdx.y * 64;
  if (t < 64) vsh[t] = v_g[n0 + t];
  {
    const int r = t >> 4;         // 0..15
    const int c4 = (t & 15) * 4;  // 0..60
#pragma unroll
    for (int p = 0; p < 4; ++p) {
      float4 f =
          *(const float4*)&XL[(size_t)(n0 + r + 16 * p) * 4096 + c0 + c4];
      *(float4*)&T[(r + 16 * p) * 68 + c4] = f;
    }
  }
  __syncthreads();
  const int cl = t >> 2;        // 0..63
  const int nb = (t & 3) * 16;  // 0,16,32,48
  __align__(16) __hip_bfloat16 hbuf[16];
  __align__(16) __hip_bfloat16 lbuf[16];
#pragma unroll
  for (int j = 0; j < 16; ++j) {
    float xv = T[(nb + j) * 68 + cl] * vsh[nb + j];
    __hip_bfloat16 h = __float2bfloat16(xv);
    hbuf[j] = h;
    lbuf[j] = __float2bfloat16(xv - __bfloat162float(h));
  }
  const size_t off = (size_t)(c0 + cl) * 1024 + n0 + nb;
  *(uint4*)&XTh[off] = *(uint4*)&hbuf[0];
  *(uint4*)&XTh[off + 8] = *(uint4*)&hbuf[8];
  *(uint4*)&XTl[off] = *(uint4*)&lbuf[0];
  *(uint4*)&XTl[off + 8] = *(uint4*)&lbuf[8];
}

// ---------------- kernel 3 (bf16): out = u ⊙ (Eh*XTh + El*XTh + Eh*XTl) ------
// D[m=1024][c=4096], 128x128 block tile, 4 waves each 64x64 of 16x16x32 MFMA.
#define LSTR 72  // padded LDS row stride (elements)
__global__ __launch_bounds__(256) void k_gemm3(
    const ushort* __restrict__ Eh, const ushort* __restrict__ El,
    const ushort* __restrict__ XTh, const ushort* __restrict__ XTl,
    const float* __restrict__ u_g, float* __restrict__ out) {
  __shared__ ushort As[128 * LSTR];
  __shared__ ushort Xs[128 * LSTR];
  __shared__ float ush[128];
  const int t = threadIdx.x;
  const int m0 = blockIdx.x * 128;
  const int c0 = blockIdx.y * 128;
  const int wid = t >> 6, lane = t & 63;
  const int wm = (wid & 1) * 64, wc = (wid >> 1) * 64;
  const int lm = lane & 15, q = lane >> 4;
  const int sr = t >> 1;        // staging row 0..127
  const int sc = (t & 1) * 32;  // staging k-offset: [sc, sc+32)
  if (t < 128) ush[t] = u_g[m0 + t];

  float4v acc[4][4];
#pragma unroll
  for (int i = 0; i < 4; ++i)
#pragma unroll
    for (int j = 0; j < 4; ++j) acc[i][j] = (float4v){0.f, 0.f, 0.f, 0.f};

  for (int seg = 0; seg < 3; ++seg) {
    const ushort* Ag = (seg == 1) ? El : Eh;
    const ushort* Xg = (seg == 2) ? XTl : XTh;
    for (int k0 = 0; k0 < 1024; k0 += 64) {
      __syncthreads();
      const ushort* ag = Ag + (size_t)(m0 + sr) * 1024 + k0 + sc;
      const ushort* xg = Xg + (size_t)(c0 + sr) * 1024 + k0 + sc;
      uint4 a0 = *(const uint4*)(ag);
      uint4 a1 = *(const uint4*)(ag + 8);
      uint4 a2 = *(const uint4*)(ag + 16);
      uint4 a3 = *(const uint4*)(ag + 24);
      uint4 x0 = *(const uint4*)(xg);
      uint4 x1 = *(const uint4*)(xg + 8);
      uint4 x2 = *(const uint4*)(xg + 16);
      uint4 x3 = *(const uint4*)(xg + 24);
      *(uint4*)&As[sr * LSTR + sc] = a0;
      *(uint4*)&As[sr * LSTR + sc + 8] = a1;
      *(uint4*)&As[sr * LSTR + sc + 16] = a2;
      *(uint4*)&As[sr * LSTR + sc + 24] = a3;
      *(uint4*)&Xs[sr * LSTR + sc] = x0;
      *(uint4*)&Xs[sr * LSTR + sc + 8] = x1;
      *(uint4*)&Xs[sr * LSTR + sc + 16] = x2;
      *(uint4*)&Xs[sr * LSTR + sc + 24] = x3;
      __syncthreads();
#pragma unroll
      for (int kk = 0; kk < 2; ++kk) {
        short8 af[4], xf[4];
#pragma unroll
        for (int i = 0; i < 4; ++i)
          af[i] = *(const short8*)&As[(wm + 16 * i + lm) * LSTR + kk * 32 +
                                      q * 8];
#pragma unroll
        for (int j = 0; j < 4; ++j)
          xf[j] = *(const short8*)&Xs[(wc + 16 * j + lm) * LSTR + kk * 32 +
                                      q * 8];
#pragma unroll
        for (int i = 0; i < 4; ++i)
#pragma unroll
          for (int j = 0; j < 4; ++j)
            acc[i][j] = __builtin_amdgcn_mfma_f32_16x16x32_bf16(
                af[i], xf[j], acc[i][j], 0, 0, 0);
      }
    }
  }
  // epilogue: D row = q*4 + reg, col = lm (m89-verified); scale by u_m
#pragma unroll
  for (int i = 0; i < 4; ++i) {
#pragma unroll
    for (int j = 0; j < 4; ++j) {
      const int ml = wm + 16 * i + q * 4;
      const int m = m0 + ml;
      const int c = c0 + wc + 16 * j + lm;
      const int bb = c >> 6, o = c & 63;
      float* dst = out + (size_t)bb * 65536 + (size_t)m * 64 + o;
#pragma unroll
      for (int r = 0; r < 4; ++r) dst[64 * r] = acc[i][j][r] * ush[ml + r];
    }
  }
}

// ---------------- kernel 3 (fp32 fallback): out = u ⊙ (E0·(v⊙XL)) ------------
__global__ __launch_bounds__(256) void k_gemm(const float* __restrict__ E0,
                                              const float* __restrict__ XL,
                                              const float* __restrict__ u_g,
                                              const float* __restrict__ v_g,
                                              float* __restrict__ out) {
  __shared__ float Asm[32][132];
  __shared__ float Xsm[32][132];
  const int t = threadIdx.x;
  const int m0 = blockIdx.x * 128;
  const int c0 = blockIdx.y * 128;
  const int my8 = (t >> 4) * 8;
  const int cx8 = (t & 15) * 8;
  const int kk = t & 31;
  const int rr = t >> 5;
  float acc[8][8] = {};

  for (int k0 = 0; k0 < 1024; k0 += 32) {
#pragma unroll
    for (int s = 0; s < 16; ++s)
      Asm[kk][rr + 8 * s] = E0[(size_t)(m0 + rr + 8 * s) * 1024 + k0 + kk];
#pragma unroll
    for (int s = 0; s < 4; ++s) {
      const int krow = k0 + rr + 8 * s;
      float vk = v_g[krow];
      float4 f = *(const float4*)&XL[(size_t)krow * 4096 + c0 + kk * 4];
      f.x *= vk;
      f.y *= vk;
      f.z *= vk;
      f.w *= vk;
      *(float4*)&Xsm[rr + 8 * s][kk * 4] = f;
    }
    __syncthreads();
#pragma unroll
    for (int k = 0; k < 32; ++k) {
      float a[8], xv[8];
      *(float4*)&a[0] = *(const float4*)&Asm[k][my8];
      *(float4*)&a[4] = *(const float4*)&Asm[k][my8 + 4];
      *(float4*)&xv[0] = *(const float4*)&Xsm[k][cx8];
      *(float4*)&xv[4] = *(const float4*)&Xsm[k][cx8 + 4];
#pragma unroll
      for (int i = 0; i < 8; ++i)
#pragma unroll
        for (int j = 0; j < 8; ++j) acc[i][j] += a[i] * xv[j];
    }
    __syncthreads();
  }

#pragma unroll
  for (int i = 0; i < 8; ++i) {
    const int m = m0 + my8 + i;
    const float um = u_g[m];
    const int c = c0 + cx8;
    const int bb = c >> 6, o = c & 63;
    float* dst = out + (size_t)bb * 65536 + (size_t)m * 64 + o;
#pragma unroll
    for (int j = 0; j < 8; ++j) dst[j < 4 ? j : j] = 0;  // placeholder avoided
#pragma unroll
    for (int j = 0; j < 8; ++j) dst[j] = acc[i][j] * um;
  }
}

// ---------------- launcher ---------------------------------------------------
extern "C" void kernel_launch(void* const* d_in, const int* in_sizes, int n_in,
                              void* d_out, int out_size, void* d_ws,
                              size_t ws_size, hipStream_t stream) {
  (void)in_sizes;
  (void)n_in;
  (void)out_size;
  const float* x = (const float*)d_in[0];
  const float* Alog = (const float*)d_in[1];
  const float* W1 = (const float*)d_in[2];
  const float* WV = (const float*)d_in[3];
  float* out = (float*)d_out;

  char* ws = (char*)d_ws;
  const size_t MB = 1024 * 1024;
  const size_t KB = 1024;
  const bool use_bf16 = ws_size >= (40 * MB + 256 * KB);

  float* E0;
  float* XL;
  float* P;
  float* u_g;
  float* v_g;
  unsigned* ctrl;
  __hip_bfloat16 *Eh = nullptr, *El = nullptr, *XTh = nullptr, *XTl = nullptr;
  if (use_bf16) {
    E0 = (float*)(ws);                      // 4 MB
    XL = (float*)(ws + 4 * MB);             // 16 MB
    Eh = (__hip_bfloat16*)(ws + 20 * MB);   // 2 MB
    El = (__hip_bfloat16*)(ws + 22 * MB);   // 2 MB
    XTh = (__hip_bfloat16*)(ws + 24 * MB);  // 8 MB
    XTl = (__hip_bfloat16*)(ws + 32 * MB);  // 8 MB -> 40 MB
    P = (float*)(ws + 40 * MB);             // 2*16*4 KB = 128 KB
    u_g = (float*)(ws + 40 * MB + 128 * KB);  // 4 KB
    v_g = (float*)(ws + 40 * MB + 132 * KB);  // 4 KB
    ctrl = (unsigned*)(ws + 40 * MB + 136 * KB);  // 4 KB
  } else {
    E0 = (float*)(ws);                      // 4 MB
    XL = (float*)(ws + 4 * MB);             // 16 MB
    P = (float*)(ws + 20 * MB);             // 128 KB
    u_g = (float*)(ws + 20 * MB + 128 * KB);
    v_g = (float*)(ws + 20 * MB + 132 * KB);
    ctrl = (unsigned*)(ws + 20 * MB + 136 * KB);
  }

  hipMemsetAsync(ctrl, 0, 4096, stream);
  hipLaunchKernelGGL(k_front, dim3(NBAR + 256), dim3(1024), 0, stream, x, Alog,
                     W1, WV, E0, Eh, El, P, ctrl, u_g, v_g, XL,
                     use_bf16 ? 1 : 0);
  if (use_bf16) {
    hipLaunchKernelGGL(k_xt, dim3(16, 64), dim3(256), 0, stream, XL, v_g, XTh,
                       XTl);
    hipLaunchKernelGGL(k_gemm3, dim3(8, 32), dim3(256), 0, stream,
                       (const ushort*)Eh, (const ushort*)El, (const ushort*)XTh,
                       (const ushort*)XTl, u_g, out);
  } else {
    hipLaunchKernelGGL(k_gemm, dim3(8, 32), dim3(256), 0, stream, E0, XL, u_g,
                       v_g, out);
  }
}